// Round 1
// baseline (448.533 us; speedup 1.0000x reference)
//
#include <hip/hip_runtime.h>
#include <hip/hip_bf16.h>

// BERT_SCL: loss = 0.9 * supcon(cls_emb, labels) + 0.1 * CE(pooled@W.T + b, labels)
// d_out[0] = loss, d_out[1..57344] = logits (8192 x 7, f32)
//
// supcon path: en = rows of cls_emb normalized and scaled by 1/sqrt(TEMP), cast bf16.
// S_ij = en_i . en_j  (= cos/TEMP). Since S <= M = 1/TEMP, use fixed-max logsumexp:
//   lse_i = M + log( sum_{j != i} exp(S_ij - M) )
//   per_anchor_i = lse_i - possum_i / n_i   (n_i = hist[label_i]-1)
// contrastive = sum_i per_anchor_i.

#define B_N 8192
#define D_K 768
#define NLAB 7
#define MBOUND 3.3333333333333335f /* 1/TEMP */
#define RTINV 1.8257418583505538f  /* 1/sqrt(TEMP) */

typedef short s16x8 __attribute__((ext_vector_type(8)));
typedef float f32x4 __attribute__((ext_vector_type(4)));

__device__ __forceinline__ void gl2lds16(const void* g, void* l) {
  __builtin_amdgcn_global_load_lds(
      (const __attribute__((address_space(1))) void*)g,
      (__attribute__((address_space(3))) void*)l, 16, 0, 0);
}

// ---- kernel 1: normalize cls rows -> bf16 en (scaled by 1/sqrt(TEMP)), label hist ----
__global__ __launch_bounds__(256) void k_norm(const float* __restrict__ cls,
                                              const int* __restrict__ labels,
                                              unsigned short* __restrict__ en,
                                              int* __restrict__ hist) {
  int row = blockIdx.x * 4 + (threadIdx.x >> 6);
  int lane = threadIdx.x & 63;
  const float* src = cls + (size_t)row * D_K;
  float x[12];
  float ss = 0.f;
#pragma unroll
  for (int j = 0; j < 12; ++j) { x[j] = src[j * 64 + lane]; ss += x[j] * x[j]; }
#pragma unroll
  for (int m = 1; m < 64; m <<= 1) ss += __shfl_xor(ss, m);
  float sc = rsqrtf(ss) * RTINV;
  unsigned short* dst = en + (size_t)row * D_K;
#pragma unroll
  for (int j = 0; j < 12; ++j) {
    __hip_bfloat16 h = __float2bfloat16(x[j] * sc);
    dst[j * 64 + lane] = *reinterpret_cast<unsigned short*>(&h);
  }
  if (lane == 0) atomicAdd(&hist[labels[row]], 1);
}

// ---- kernel 2: logits = pooled @ W.T + b ; CE sum ----
__global__ __launch_bounds__(256) void k_logits_ce(
    const float* __restrict__ pooled, const int* __restrict__ labels,
    const float* __restrict__ W, const float* __restrict__ bias,
    float* __restrict__ logits_out, float* __restrict__ ce_accum) {
  int row = blockIdx.x * 4 + (threadIdx.x >> 6);
  int lane = threadIdx.x & 63;
  const float* p = pooled + (size_t)row * D_K;
  float acc[NLAB];
#pragma unroll
  for (int c = 0; c < NLAB; ++c) acc[c] = 0.f;
#pragma unroll
  for (int j = 0; j < 12; ++j) {
    float x = p[j * 64 + lane];
#pragma unroll
    for (int c = 0; c < NLAB; ++c) acc[c] += x * W[c * D_K + j * 64 + lane];
  }
#pragma unroll
  for (int c = 0; c < NLAB; ++c)
#pragma unroll
    for (int m = 1; m < 64; m <<= 1) acc[c] += __shfl_xor(acc[c], m);
  if (lane == 0) {
    float l[NLAB], mx = -1e30f;
#pragma unroll
    for (int c = 0; c < NLAB; ++c) { l[c] = acc[c] + bias[c]; mx = fmaxf(mx, l[c]); }
    float se = 0.f;
#pragma unroll
    for (int c = 0; c < NLAB; ++c) se += __expf(l[c] - mx);
    float lse = mx + __logf(se);
    atomicAdd(ce_accum, lse - l[labels[row]]);
    float* o = logits_out + (size_t)row * NLAB;
#pragma unroll
    for (int c = 0; c < NLAB; ++c) o[c] = l[c];
  }
}

// ---- kernel 3: the big one. 128x128 S-tiles via bf16 MFMA, streamed reduction ----
// grid (64, 64): bi = row tile, bj = col tile. BK=64, 12 k-chunks.
// LDS layout: chunk c (8 bf16 = 16B) of row r stored at slot r*8 + ((c+r)&7)
// (rotate swizzle -> conflict-balanced ds_read_b128, swizzle applied on global src).
__global__ __launch_bounds__(256) void k_scl(const unsigned short* __restrict__ en,
                                             const int* __restrict__ labels,
                                             float* __restrict__ rse,
                                             float* __restrict__ rsp) {
  __shared__ __align__(16) unsigned short As[128 * 64];
  __shared__ __align__(16) unsigned short Bs[128 * 64];
  const int bi = blockIdx.x, bj = blockIdx.y;
  const int i0 = bi * 128, j0 = bj * 128;
  const int tid = threadIdx.x, wv = tid >> 6, lane = tid & 63;
  const int quad = lane >> 4, cix = lane & 15;
  const int rowTile = 64 * (wv >> 1), colTile = 64 * (wv & 1);

  f32x4 acc[4][4] = {};

  for (int kc = 0; kc < 12; ++kc) {
    __syncthreads();  // previous iter's ds_reads done before overwrite
#pragma unroll
    for (int it = 0; it < 4; ++it) {
      int s = it * 256 + tid;
      int r = s >> 3;
      int c = ((s & 7) - r) & 7;  // inverse of write swizzle
      size_t goffA = (size_t)(i0 + r) * D_K + kc * 64 + c * 8;
      size_t goffB = (size_t)(j0 + r) * D_K + kc * 64 + c * 8;
      int lbase = (it * 256 + wv * 64) * 16;  // wave-uniform LDS base (bytes)
      gl2lds16(en + goffA, (char*)As + lbase);
      gl2lds16(en + goffB, (char*)Bs + lbase);
    }
    __syncthreads();  // staging visible (vmcnt drained at barrier)
#pragma unroll
    for (int h = 0; h < 2; ++h) {
      s16x8 aF[4], bF[4];
      const int cc = quad + 4 * h;
#pragma unroll
      for (int mt = 0; mt < 4; ++mt) {
        int r = rowTile + 16 * mt + cix;
        aF[mt] = *reinterpret_cast<const s16x8*>((const char*)As +
                                                 (r * 8 + ((cc + r) & 7)) * 16);
      }
#pragma unroll
      for (int nt = 0; nt < 4; ++nt) {
        int r = colTile + 16 * nt + cix;
        bF[nt] = *reinterpret_cast<const s16x8*>((const char*)Bs +
                                                 (r * 8 + ((cc + r) & 7)) * 16);
      }
#pragma unroll
      for (int mt = 0; mt < 4; ++mt)
#pragma unroll
        for (int nt = 0; nt < 4; ++nt)
          acc[mt][nt] = __builtin_amdgcn_mfma_f32_16x16x32_bf16(
              aF[mt], bF[nt], acc[mt][nt], 0, 0, 0);
    }
  }

  // epilogue: per-element exp / positive masking, reduce over 16 col-lanes, atomics
  const bool diagB = (bi == bj);
  int lcol[4];
#pragma unroll
  for (int nt = 0; nt < 4; ++nt) lcol[nt] = labels[j0 + colTile + 16 * nt + cix];

#pragma unroll
  for (int mt = 0; mt < 4; ++mt) {
    int rowbase = i0 + rowTile + 16 * mt + quad * 4;
    int4 lr = *reinterpret_cast<const int4*>(labels + rowbase);
    const int* lrp = reinterpret_cast<const int*>(&lr);
    float rs_e[4] = {0.f, 0.f, 0.f, 0.f}, rs_p[4] = {0.f, 0.f, 0.f, 0.f};
#pragma unroll
    for (int nt = 0; nt < 4; ++nt) {
      int gcol = j0 + colTile + 16 * nt + cix;
      int lc = lcol[nt];
#pragma unroll
      for (int rg = 0; rg < 4; ++rg) {
        float s = acc[mt][nt][rg];
        bool dg = diagB && ((rowbase + rg) == gcol);
        rs_e[rg] += dg ? 0.f : __expf(s - MBOUND);
        rs_p[rg] += ((lrp[rg] == lc) && !dg) ? s : 0.f;
      }
    }
#pragma unroll
    for (int rg = 0; rg < 4; ++rg) {
#pragma unroll
      for (int m = 1; m <= 8; m <<= 1) {
        rs_e[rg] += __shfl_xor(rs_e[rg], m);
        rs_p[rg] += __shfl_xor(rs_p[rg], m);
      }
    }
    if (cix == 0) {
#pragma unroll
      for (int rg = 0; rg < 4; ++rg) {
        atomicAdd(&rse[rowbase + rg], rs_e[rg]);
        atomicAdd(&rsp[rowbase + rg], rs_p[rg]);
      }
    }
  }
}

// ---- kernel 4: per-row per_anchor, sum -> contrastive ----
__global__ __launch_bounds__(256) void k_rowfinal(const float* __restrict__ rse,
                                                  const float* __restrict__ rsp,
                                                  const int* __restrict__ labels,
                                                  const int* __restrict__ hist,
                                                  float* __restrict__ contr) {
  int i = blockIdx.x * 256 + threadIdx.x;
  int ni = hist[labels[i]] - 1;
  float per = 0.f;
  if (ni > 0) per = MBOUND + __logf(rse[i]) - rsp[i] / (float)ni;
#pragma unroll
  for (int m = 1; m < 64; m <<= 1) per += __shfl_xor(per, m);
  if ((threadIdx.x & 63) == 0) atomicAdd(contr, per);
}

// ---- kernel 5: final scalar combine ----
__global__ void k_final(const float* __restrict__ ce, const float* __restrict__ contr,
                        float* __restrict__ out) {
  if (threadIdx.x == 0 && blockIdx.x == 0)
    out[0] = 0.9f * contr[0] + (1.0f - 0.9f) * (ce[0] / (float)B_N);
}

extern "C" void kernel_launch(void* const* d_in, const int* in_sizes, int n_in,
                              void* d_out, int out_size, void* d_ws, size_t ws_size,
                              hipStream_t stream) {
  const float* cls    = (const float*)d_in[0];
  const float* pooled = (const float*)d_in[1];
  const int*   labels = (const int*)d_in[2];
  const float* W      = (const float*)d_in[3];
  const float* bias   = (const float*)d_in[4];
  float* out = (float*)d_out;

  // workspace layout (needs ~12.65 MB)
  char* ws = (char*)d_ws;
  unsigned short* en = (unsigned short*)ws;            // 8192*768*2 = 12582912 B
  size_t off = (size_t)B_N * D_K * 2;
  float* rse   = (float*)(ws + off);                   // 8192 f32
  float* rsp   = (float*)(ws + off + 32768);           // 8192 f32
  int*   hist  = (int*)(ws + off + 65536);             // 7 int (pad 32)
  float* cesum = (float*)(ws + off + 65568);           // 1 f32
  float* contr = (float*)(ws + off + 65572);           // 1 f32

  hipMemsetAsync(ws + off, 0, 65576, stream);  // zero all accumulators

  k_norm<<<B_N / 4, 256, 0, stream>>>(cls, labels, en, hist);
  k_logits_ce<<<B_N / 4, 256, 0, stream>>>(pooled, labels, W, bias, out + 1, cesum);
  dim3 g(B_N / 128, B_N / 128);
  k_scl<<<g, 256, 0, stream>>>(en, labels, rse, rsp);
  k_rowfinal<<<B_N / 256, 256, 0, stream>>>(rse, rsp, labels, hist, contr);
  k_final<<<1, 64, 0, stream>>>(cesum, contr, out);
}

// Round 2
// 438.108 us; speedup vs baseline: 1.0238x; 1.0238x over previous
//
#include <hip/hip_runtime.h>
#include <hip/hip_bf16.h>

// BERT_SCL: loss = 0.9 * supcon(cls_emb, labels) + 0.1 * CE(pooled@W.T + b, labels)
// d_out[0] = loss, d_out[1..57344] = logits (8192 x 7, f32)
//
// supcon: en = rows of cls_emb normalized, scaled by 1/sqrt(TEMP), cast bf16.
// S_ij = en_i . en_j = cos/TEMP <= M = 1/TEMP  ->  fixed-max logsumexp:
//   lse_i = M + log( sum_{j != i} exp(S_ij - M) )
//   per_anchor_i = lse_i - possum_i / n_i   (n_i = hist[label_i]-1)
// S is SYMMETRIC and the positive mask is symmetric -> compute only tiles
// bi <= bj (2080 of 4096); off-diagonal tiles contribute row-sums AND
// column-sums (S_ji = S_ij).

#define B_N 8192
#define D_K 768
#define NLAB 7
#define MBOUND 3.3333333333333335f /* 1/TEMP */
#define RTINV 1.8257418583505538f  /* 1/sqrt(TEMP) */

typedef short s16x8 __attribute__((ext_vector_type(8)));
typedef float f32x4 __attribute__((ext_vector_type(4)));

__device__ __forceinline__ void gl2lds16(const void* g, void* l) {
  __builtin_amdgcn_global_load_lds(
      (const __attribute__((address_space(1))) void*)g,
      (__attribute__((address_space(3))) void*)l, 16, 0, 0);
}

// ---- kernel 1: normalize cls rows -> bf16 en (scaled by 1/sqrt(TEMP)), label hist ----
__global__ __launch_bounds__(256) void k_norm(const float* __restrict__ cls,
                                              const int* __restrict__ labels,
                                              unsigned short* __restrict__ en,
                                              int* __restrict__ hist) {
  int row = blockIdx.x * 4 + (threadIdx.x >> 6);
  int lane = threadIdx.x & 63;
  const float4* src = (const float4*)(cls + (size_t)row * D_K);
  float4 x[3];
  float ss = 0.f;
#pragma unroll
  for (int j = 0; j < 3; ++j) {
    x[j] = src[j * 64 + lane];
    ss += x[j].x * x[j].x + x[j].y * x[j].y + x[j].z * x[j].z + x[j].w * x[j].w;
  }
#pragma unroll
  for (int m = 1; m < 64; m <<= 1) ss += __shfl_xor(ss, m);
  float sc = rsqrtf(ss) * RTINV;
  ushort4* dst = (ushort4*)(en + (size_t)row * D_K);
#pragma unroll
  for (int j = 0; j < 3; ++j) {
    const float* xv = reinterpret_cast<const float*>(&x[j]);
    ushort4 o;
    unsigned short* ov = reinterpret_cast<unsigned short*>(&o);
#pragma unroll
    for (int k = 0; k < 4; ++k) {
      __hip_bfloat16 h = __float2bfloat16(xv[k] * sc);
      ov[k] = *reinterpret_cast<unsigned short*>(&h);
    }
    dst[j * 64 + lane] = o;
  }
  if (lane == 0) atomicAdd(&hist[labels[row]], 1);
}

// ---- kernel 2: logits = pooled @ W.T + b ; CE sum ----
__global__ __launch_bounds__(256) void k_logits_ce(
    const float* __restrict__ pooled, const int* __restrict__ labels,
    const float* __restrict__ W, const float* __restrict__ bias,
    float* __restrict__ logits_out, float* __restrict__ ce_accum) {
  int row = blockIdx.x * 4 + (threadIdx.x >> 6);
  int lane = threadIdx.x & 63;
  const float4* p4 = (const float4*)(pooled + (size_t)row * D_K);
  float acc[NLAB];
#pragma unroll
  for (int c = 0; c < NLAB; ++c) acc[c] = 0.f;
#pragma unroll
  for (int j = 0; j < 3; ++j) {
    float4 x = p4[j * 64 + lane];
#pragma unroll
    for (int c = 0; c < NLAB; ++c) {
      float4 w = ((const float4*)(W + c * D_K))[j * 64 + lane];
      acc[c] += x.x * w.x + x.y * w.y + x.z * w.z + x.w * w.w;
    }
  }
#pragma unroll
  for (int c = 0; c < NLAB; ++c)
#pragma unroll
    for (int m = 1; m < 64; m <<= 1) acc[c] += __shfl_xor(acc[c], m);
  if (lane == 0) {
    float l[NLAB], mx = -1e30f;
#pragma unroll
    for (int c = 0; c < NLAB; ++c) { l[c] = acc[c] + bias[c]; mx = fmaxf(mx, l[c]); }
    float se = 0.f;
#pragma unroll
    for (int c = 0; c < NLAB; ++c) se += __expf(l[c] - mx);
    float lse = mx + __logf(se);
    atomicAdd(ce_accum, lse - l[labels[row]]);
    float* o = logits_out + (size_t)row * NLAB;
#pragma unroll
    for (int c = 0; c < NLAB; ++c) o[c] = l[c];
  }
}

// ---- kernel 3: S-tiles via bf16 MFMA, UPPER-TRIANGULAR blocks only ----
// 2080 blocks, linear id -> (bi <= bj). BK=64, 12 k-chunks.
// LDS: chunk c (16B) of row r at slot r*8 + ((c+r)&7) (rotate swizzle on the
// global source address; LDS dest stays wave-uniform base + lane*16).
__global__ __launch_bounds__(256) void k_scl(const unsigned short* __restrict__ en,
                                             const int* __restrict__ labels,
                                             float* __restrict__ rse,
                                             float* __restrict__ rsp) {
  __shared__ __align__(16) unsigned short As[128 * 64];
  __shared__ __align__(16) unsigned short Bs[128 * 64];
  // triangular decode (block-uniform scalar loop, <=64 iters)
  int bi = 0, rem = blockIdx.x, width = 64;
  while (rem >= width) { rem -= width; ++bi; --width; }
  const int bj = bi + rem;
  const int i0 = bi * 128, j0 = bj * 128;
  const int tid = threadIdx.x, wv = tid >> 6, lane = tid & 63;
  const int quad = lane >> 4, cix = lane & 15;
  const int rowTile = 64 * (wv >> 1), colTile = 64 * (wv & 1);

  // precompute staging offsets (advance by 64 elements per kc)
  int goffA[4], goffB[4], lbase[4];
#pragma unroll
  for (int it = 0; it < 4; ++it) {
    int s = it * 256 + tid;
    int r = s >> 3;
    int c = ((s & 7) - r) & 7;  // inverse of write swizzle
    goffA[it] = (i0 + r) * D_K + c * 8;
    goffB[it] = (j0 + r) * D_K + c * 8;
    lbase[it] = (it * 256 + wv * 64) * 16;
  }

  f32x4 acc[4][4] = {};

  for (int kc = 0; kc < 12; ++kc) {
    __syncthreads();
#pragma unroll
    for (int it = 0; it < 4; ++it) {
      gl2lds16(en + goffA[it] + kc * 64, (char*)As + lbase[it]);
      gl2lds16(en + goffB[it] + kc * 64, (char*)Bs + lbase[it]);
    }
    __syncthreads();
#pragma unroll
    for (int h = 0; h < 2; ++h) {
      s16x8 aF[4], bF[4];
      const int cc = quad + 4 * h;
#pragma unroll
      for (int mt = 0; mt < 4; ++mt) {
        int r = rowTile + 16 * mt + cix;
        aF[mt] = *reinterpret_cast<const s16x8*>((const char*)As +
                                                 (r * 8 + ((cc + r) & 7)) * 16);
      }
#pragma unroll
      for (int nt = 0; nt < 4; ++nt) {
        int r = colTile + 16 * nt + cix;
        bF[nt] = *reinterpret_cast<const s16x8*>((const char*)Bs +
                                                 (r * 8 + ((cc + r) & 7)) * 16);
      }
#pragma unroll
      for (int mt = 0; mt < 4; ++mt)
#pragma unroll
        for (int nt = 0; nt < 4; ++nt)
          acc[mt][nt] = __builtin_amdgcn_mfma_f32_16x16x32_bf16(
              aF[mt], bF[nt], acc[mt][nt], 0, 0, 0);
    }
  }

  // ---- epilogue ----
  const bool diagB = (bi == bj);
  int lcol[4];
#pragma unroll
  for (int nt = 0; nt < 4; ++nt) lcol[nt] = labels[j0 + colTile + 16 * nt + cix];

  float ce_col[4] = {0.f, 0.f, 0.f, 0.f};  // per-nt column partials (this lane's rows)
  float cp_col[4] = {0.f, 0.f, 0.f, 0.f};

#pragma unroll
  for (int mt = 0; mt < 4; ++mt) {
    int rowbase = i0 + rowTile + 16 * mt + quad * 4;
    int4 lr = *reinterpret_cast<const int4*>(labels + rowbase);
    const int* lrp = reinterpret_cast<const int*>(&lr);
    float rs_e[4] = {0.f, 0.f, 0.f, 0.f}, rs_p[4] = {0.f, 0.f, 0.f, 0.f};
#pragma unroll
    for (int nt = 0; nt < 4; ++nt) {
      int gcol = j0 + colTile + 16 * nt + cix;
      int lc = lcol[nt];
#pragma unroll
      for (int rg = 0; rg < 4; ++rg) {
        float s = acc[mt][nt][rg];
        bool dg = diagB && ((rowbase + rg) == gcol);
        float e = dg ? 0.f : __expf(s - MBOUND);
        float p = ((lrp[rg] == lc) && !dg) ? s : 0.f;
        rs_e[rg] += e;
        rs_p[rg] += p;
        ce_col[nt] += e;
        cp_col[nt] += p;
      }
    }
    // row reduce over the 16 column lanes
#pragma unroll
    for (int rg = 0; rg < 4; ++rg) {
#pragma unroll
      for (int m = 1; m <= 8; m <<= 1) {
        rs_e[rg] += __shfl_xor(rs_e[rg], m);
        rs_p[rg] += __shfl_xor(rs_p[rg], m);
      }
    }
    if (cix == 0) {
#pragma unroll
      for (int rg = 0; rg < 4; ++rg) {
        atomicAdd(&rse[rowbase + rg], rs_e[rg]);
        atomicAdd(&rsp[rowbase + rg], rs_p[rg]);
      }
    }
  }

  // column side: S_ji = S_ij, only for strictly-upper blocks
  if (!diagB) {
#pragma unroll
    for (int nt = 0; nt < 4; ++nt) {
      // sum over the wave's 64 rows: lanes sharing cix differ in bits 4..5
      ce_col[nt] += __shfl_xor(ce_col[nt], 16);
      ce_col[nt] += __shfl_xor(ce_col[nt], 32);
      cp_col[nt] += __shfl_xor(cp_col[nt], 16);
      cp_col[nt] += __shfl_xor(cp_col[nt], 32);
    }
    if (quad == 0) {
#pragma unroll
      for (int nt = 0; nt < 4; ++nt) {
        int gcol = j0 + colTile + 16 * nt + cix;
        atomicAdd(&rse[gcol], ce_col[nt]);
        atomicAdd(&rsp[gcol], cp_col[nt]);
      }
    }
  }
}

// ---- kernel 4: per-row per_anchor, sum -> contrastive ----
__global__ __launch_bounds__(256) void k_rowfinal(const float* __restrict__ rse,
                                                  const float* __restrict__ rsp,
                                                  const int* __restrict__ labels,
                                                  const int* __restrict__ hist,
                                                  float* __restrict__ contr) {
  int i = blockIdx.x * 256 + threadIdx.x;
  int ni = hist[labels[i]] - 1;
  float per = 0.f;
  if (ni > 0) per = MBOUND + __logf(rse[i]) - rsp[i] / (float)ni;
#pragma unroll
  for (int m = 1; m < 64; m <<= 1) per += __shfl_xor(per, m);
  if ((threadIdx.x & 63) == 0) atomicAdd(contr, per);
}

// ---- kernel 5: final scalar combine ----
__global__ void k_final(const float* __restrict__ ce, const float* __restrict__ contr,
                        float* __restrict__ out) {
  if (threadIdx.x == 0 && blockIdx.x == 0)
    out[0] = 0.9f * contr[0] + (1.0f - 0.9f) * (ce[0] / (float)B_N);
}

extern "C" void kernel_launch(void* const* d_in, const int* in_sizes, int n_in,
                              void* d_out, int out_size, void* d_ws, size_t ws_size,
                              hipStream_t stream) {
  const float* cls    = (const float*)d_in[0];
  const float* pooled = (const float*)d_in[1];
  const int*   labels = (const int*)d_in[2];
  const float* W      = (const float*)d_in[3];
  const float* bias   = (const float*)d_in[4];
  float* out = (float*)d_out;

  // workspace layout (~12.65 MB)
  char* ws = (char*)d_ws;
  unsigned short* en = (unsigned short*)ws;            // 8192*768*2 = 12582912 B
  size_t off = (size_t)B_N * D_K * 2;
  float* rse   = (float*)(ws + off);                   // 8192 f32
  float* rsp   = (float*)(ws + off + 32768);           // 8192 f32
  int*   hist  = (int*)(ws + off + 65536);             // 7 int (pad 32)
  float* cesum = (float*)(ws + off + 65568);           // 1 f32
  float* contr = (float*)(ws + off + 65572);           // 1 f32

  hipMemsetAsync(ws + off, 0, 65576, stream);  // zero all accumulators

  k_norm<<<B_N / 4, 256, 0, stream>>>(cls, labels, en, hist);
  k_logits_ce<<<B_N / 4, 256, 0, stream>>>(pooled, labels, W, bias, out + 1, cesum);
  k_scl<<<2080, 256, 0, stream>>>(en, labels, rse, rsp);
  k_rowfinal<<<B_N / 256, 256, 0, stream>>>(rse, rsp, labels, hist, contr);
  k_final<<<1, 64, 0, stream>>>(cesum, contr, out);
}

// Round 3
// 330.373 us; speedup vs baseline: 1.3577x; 1.3261x over previous
//
#include <hip/hip_runtime.h>
#include <hip/hip_bf16.h>

// BERT_SCL: loss = 0.9 * supcon(cls_emb, labels) + 0.1 * CE(pooled@W.T + b, labels)
// d_out[0] = loss, d_out[1..57344] = logits (8192 x 7, f32)
//
// supcon: en = rows of cls_emb normalized, scaled by 1/sqrt(TEMP), cast bf16.
// S_ij = en_i . en_j = cos/TEMP <= M = 1/TEMP  ->  fixed-max logsumexp:
//   lse_i = M + log( sum_{j != i} exp(S_ij - M) )
//   per_anchor_i = lse_i - possum_i / n_i   (n_i = hist[label_i]-1)
// S symmetric + symmetric positive mask -> only tiles bi <= bj (2080 of 4096);
// off-diagonal tiles emit row-sums AND column-sums.
// Block ids are SUPERTILE-swizzled (8x8 blocks) so a co-resident window's
// panel working set (~3.1 MB) fits per-XCD L2 (round-2 row-major triangular
// order spanned 12.6 MB -> FETCH_SIZE 3x, MfmaUtil halved).

#define B_N 8192
#define D_K 768
#define NLAB 7
#define MBOUND 3.3333333333333335f /* 1/TEMP */
#define RTINV 1.8257418583505538f  /* 1/sqrt(TEMP) */

typedef short s16x8 __attribute__((ext_vector_type(8)));
typedef float f32x4 __attribute__((ext_vector_type(4)));

__device__ __forceinline__ void gl2lds16(const void* g, void* l) {
  __builtin_amdgcn_global_load_lds(
      (const __attribute__((address_space(1))) void*)g,
      (__attribute__((address_space(3))) void*)l, 16, 0, 0);
}

// ---- kernel 1: normalize cls rows -> bf16 en (scaled by 1/sqrt(TEMP)), label hist ----
__global__ __launch_bounds__(256) void k_norm(const float* __restrict__ cls,
                                              const int* __restrict__ labels,
                                              unsigned short* __restrict__ en,
                                              int* __restrict__ hist) {
  int row = blockIdx.x * 4 + (threadIdx.x >> 6);
  int lane = threadIdx.x & 63;
  const float4* src = (const float4*)(cls + (size_t)row * D_K);
  float4 x[3];
  float ss = 0.f;
#pragma unroll
  for (int j = 0; j < 3; ++j) {
    x[j] = src[j * 64 + lane];
    ss += x[j].x * x[j].x + x[j].y * x[j].y + x[j].z * x[j].z + x[j].w * x[j].w;
  }
#pragma unroll
  for (int m = 1; m < 64; m <<= 1) ss += __shfl_xor(ss, m);
  float sc = rsqrtf(ss) * RTINV;
  ushort4* dst = (ushort4*)(en + (size_t)row * D_K);
#pragma unroll
  for (int j = 0; j < 3; ++j) {
    const float* xv = reinterpret_cast<const float*>(&x[j]);
    ushort4 o;
    unsigned short* ov = reinterpret_cast<unsigned short*>(&o);
#pragma unroll
    for (int k = 0; k < 4; ++k) {
      __hip_bfloat16 h = __float2bfloat16(xv[k] * sc);
      ov[k] = *reinterpret_cast<unsigned short*>(&h);
    }
    dst[j * 64 + lane] = o;
  }
  if (lane == 0) atomicAdd(&hist[labels[row]], 1);
}

// ---- kernel 2: logits = pooled @ W.T + b ; per-row CE to array (NO hot atomic) ----
__global__ __launch_bounds__(256) void k_logits_ce(
    const float* __restrict__ pooled, const int* __restrict__ labels,
    const float* __restrict__ W, const float* __restrict__ bias,
    float* __restrict__ logits_out, float* __restrict__ celoss) {
  int row = blockIdx.x * 4 + (threadIdx.x >> 6);
  int lane = threadIdx.x & 63;
  const float4* p4 = (const float4*)(pooled + (size_t)row * D_K);
  float acc[NLAB];
#pragma unroll
  for (int c = 0; c < NLAB; ++c) acc[c] = 0.f;
#pragma unroll
  for (int j = 0; j < 3; ++j) {
    float4 x = p4[j * 64 + lane];
#pragma unroll
    for (int c = 0; c < NLAB; ++c) {
      float4 w = ((const float4*)(W + c * D_K))[j * 64 + lane];
      acc[c] += x.x * w.x + x.y * w.y + x.z * w.z + x.w * w.w;
    }
  }
#pragma unroll
  for (int c = 0; c < NLAB; ++c)
#pragma unroll
    for (int m = 1; m < 64; m <<= 1) acc[c] += __shfl_xor(acc[c], m);
  if (lane == 0) {
    float l[NLAB], mx = -1e30f;
#pragma unroll
    for (int c = 0; c < NLAB; ++c) { l[c] = acc[c] + bias[c]; mx = fmaxf(mx, l[c]); }
    float se = 0.f;
#pragma unroll
    for (int c = 0; c < NLAB; ++c) se += __expf(l[c] - mx);
    float lse = mx + __logf(se);
    celoss[row] = lse - l[labels[row]];
    float* o = logits_out + (size_t)row * NLAB;
#pragma unroll
    for (int c = 0; c < NLAB; ++c) o[c] = l[c];
  }
}

// ---- kernel 3: S-tiles via bf16 MFMA, upper-triangular blocks, supertile order ----
__global__ __launch_bounds__(256) void k_scl(const unsigned short* __restrict__ en,
                                             const int* __restrict__ labels,
                                             float* __restrict__ rse,
                                             float* __restrict__ rsp) {
  __shared__ __align__(16) unsigned short As[128 * 64];
  __shared__ __align__(16) unsigned short Bs[128 * 64];

  // supertile decode: 8x8-block supertiles over the triangle, row-major;
  // diag ST = 36 blocks (local triangle), off-diag ST = 64 (row-major).
  int rem = blockIdx.x;
  int BI = 0, BJ = 0;
  for (;;) {
    int sz = (BI == BJ) ? 36 : 64;
    if (rem < sz) break;
    rem -= sz;
    if (++BJ == 8) { ++BI; BJ = BI; }
  }
  int bi, bj;
  if (BI == BJ) {
    int r = 0, w = 8;
    while (rem >= w) { rem -= w; ++r; --w; }
    bi = BI * 8 + r;
    bj = BJ * 8 + r + rem;
  } else {
    bi = BI * 8 + (rem >> 3);
    bj = BJ * 8 + (rem & 7);
  }

  const int i0 = bi * 128, j0 = bj * 128;
  const int tid = threadIdx.x, wv = tid >> 6, lane = tid & 63;
  const int quad = lane >> 4, cix = lane & 15;
  const int rowTile = 64 * (wv >> 1), colTile = 64 * (wv & 1);

  f32x4 acc[4][4] = {};

  for (int kc = 0; kc < 12; ++kc) {
    __syncthreads();
#pragma unroll
    for (int it = 0; it < 4; ++it) {
      int s = it * 256 + tid;
      int r = s >> 3;
      int c = ((s & 7) - r) & 7;  // inverse of write swizzle
      int lbase = (it * 256 + wv * 64) * 16;  // wave-uniform LDS base (bytes)
      gl2lds16(en + (size_t)(i0 + r) * D_K + kc * 64 + c * 8, (char*)As + lbase);
      gl2lds16(en + (size_t)(j0 + r) * D_K + kc * 64 + c * 8, (char*)Bs + lbase);
    }
    __syncthreads();
#pragma unroll
    for (int h = 0; h < 2; ++h) {
      s16x8 aF[4], bF[4];
      const int cc = quad + 4 * h;
#pragma unroll
      for (int mt = 0; mt < 4; ++mt) {
        int r = rowTile + 16 * mt + cix;
        aF[mt] = *reinterpret_cast<const s16x8*>((const char*)As +
                                                 (r * 8 + ((cc + r) & 7)) * 16);
      }
#pragma unroll
      for (int nt = 0; nt < 4; ++nt) {
        int r = colTile + 16 * nt + cix;
        bF[nt] = *reinterpret_cast<const s16x8*>((const char*)Bs +
                                                 (r * 8 + ((cc + r) & 7)) * 16);
      }
#pragma unroll
      for (int mt = 0; mt < 4; ++mt)
#pragma unroll
        for (int nt = 0; nt < 4; ++nt)
          acc[mt][nt] = __builtin_amdgcn_mfma_f32_16x16x32_bf16(
              aF[mt], bF[nt], acc[mt][nt], 0, 0, 0);
    }
  }

  // ---- epilogue ----
  const bool diagB = (bi == bj);
  int lcol[4];
#pragma unroll
  for (int nt = 0; nt < 4; ++nt) lcol[nt] = labels[j0 + colTile + 16 * nt + cix];

  float ce_col[4] = {0.f, 0.f, 0.f, 0.f};  // column partials (this lane's rows)
  float cp_col[4] = {0.f, 0.f, 0.f, 0.f};

#pragma unroll
  for (int mt = 0; mt < 4; ++mt) {
    int rowbase = i0 + rowTile + 16 * mt + quad * 4;
    int4 lr = *reinterpret_cast<const int4*>(labels + rowbase);
    const int* lrp = reinterpret_cast<const int*>(&lr);
    float rs_e[4] = {0.f, 0.f, 0.f, 0.f}, rs_p[4] = {0.f, 0.f, 0.f, 0.f};
#pragma unroll
    for (int nt = 0; nt < 4; ++nt) {
      int gcol = j0 + colTile + 16 * nt + cix;
      int lc = lcol[nt];
#pragma unroll
      for (int rg = 0; rg < 4; ++rg) {
        float s = acc[mt][nt][rg];
        bool dg = diagB && ((rowbase + rg) == gcol);
        float e = dg ? 0.f : __expf(s - MBOUND);
        float p = ((lrp[rg] == lc) && !dg) ? s : 0.f;
        rs_e[rg] += e;
        rs_p[rg] += p;
        ce_col[nt] += e;
        cp_col[nt] += p;
      }
    }
#pragma unroll
    for (int rg = 0; rg < 4; ++rg) {
#pragma unroll
      for (int m = 1; m <= 8; m <<= 1) {
        rs_e[rg] += __shfl_xor(rs_e[rg], m);
        rs_p[rg] += __shfl_xor(rs_p[rg], m);
      }
    }
    if (cix == 0) {
#pragma unroll
      for (int rg = 0; rg < 4; ++rg) {
        atomicAdd(&rse[rowbase + rg], rs_e[rg]);
        atomicAdd(&rsp[rowbase + rg], rs_p[rg]);
      }
    }
  }

  // column side: S_ji = S_ij, strictly-upper blocks only
  if (!diagB) {
#pragma unroll
    for (int nt = 0; nt < 4; ++nt) {
      ce_col[nt] += __shfl_xor(ce_col[nt], 16);
      ce_col[nt] += __shfl_xor(ce_col[nt], 32);
      cp_col[nt] += __shfl_xor(cp_col[nt], 16);
      cp_col[nt] += __shfl_xor(cp_col[nt], 32);
    }
    if (quad == 0) {
#pragma unroll
      for (int nt = 0; nt < 4; ++nt) {
        int gcol = j0 + colTile + 16 * nt + cix;
        atomicAdd(&rse[gcol], ce_col[nt]);
        atomicAdd(&rsp[gcol], cp_col[nt]);
      }
    }
  }
}

// ---- kernel 4: per-row 0.9*per_anchor + (0.1/B)*ce -> contr ----
__global__ __launch_bounds__(256) void k_rowfinal(const float* __restrict__ rse,
                                                  const float* __restrict__ rsp,
                                                  const int* __restrict__ labels,
                                                  const int* __restrict__ hist,
                                                  const float* __restrict__ celoss,
                                                  float* __restrict__ contr) {
  int i = blockIdx.x * 256 + threadIdx.x;
  int ni = hist[labels[i]] - 1;
  float per = 0.f;
  if (ni > 0) per = MBOUND + __logf(rse[i]) - rsp[i] / (float)ni;
  float v = 0.9f * per + (0.1f / (float)B_N) * celoss[i];
#pragma unroll
  for (int m = 1; m < 64; m <<= 1) v += __shfl_xor(v, m);
  if ((threadIdx.x & 63) == 0) atomicAdd(contr, v);
}

// ---- kernel 5: final scalar copy ----
__global__ void k_final(const float* __restrict__ contr, float* __restrict__ out) {
  if (threadIdx.x == 0 && blockIdx.x == 0) out[0] = contr[0];
}

extern "C" void kernel_launch(void* const* d_in, const int* in_sizes, int n_in,
                              void* d_out, int out_size, void* d_ws, size_t ws_size,
                              hipStream_t stream) {
  const float* cls    = (const float*)d_in[0];
  const float* pooled = (const float*)d_in[1];
  const int*   labels = (const int*)d_in[2];
  const float* W      = (const float*)d_in[3];
  const float* bias   = (const float*)d_in[4];
  float* out = (float*)d_out;

  // workspace layout (~12.7 MB)
  char* ws = (char*)d_ws;
  unsigned short* en = (unsigned short*)ws;            // 8192*768*2 = 12582912 B
  size_t off = (size_t)B_N * D_K * 2;
  float* rse    = (float*)(ws + off);                  // 8192 f32
  float* rsp    = (float*)(ws + off + 32768);          // 8192 f32
  int*   hist   = (int*)(ws + off + 65536);            // 7 int (pad 32)
  float* contr  = (float*)(ws + off + 65568);          // 1 f32
  float* celoss = (float*)(ws + off + 65536 + 4096);   // 8192 f32 (written fully)

  hipMemsetAsync(ws + off, 0, 65572, stream);  // zero rse/rsp/hist/contr

  k_norm<<<B_N / 4, 256, 0, stream>>>(cls, labels, en, hist);
  k_logits_ce<<<B_N / 4, 256, 0, stream>>>(pooled, labels, W, bias, out + 1, celoss);
  k_scl<<<2080, 256, 0, stream>>>(en, labels, rse, rsp);
  k_rowfinal<<<B_N / 256, 256, 0, stream>>>(rse, rsp, labels, hist, celoss, contr);
  k_final<<<1, 64, 0, stream>>>(contr, out);
}